// Round 7
// baseline (324.533 us; speedup 1.0000x reference)
//
#include <hip/hip_runtime.h>

// ---------------------------------------------------------------------------
// GIN 3-layer forward, fused bf16 pipeline (R7):
//   prep:   convert x->bf16, hist(dst), convert W1..3 -> k-subtiled bf16
//   CSR:    scan -> bucket scatter
//   layer:  ONE kernel: block = 32 node rows.
//           phase A: H[32][CIN] = (1+eps)x + gather-sum -> LDS (padded subtile)
//           phase B: out[32][256] = H @ W + b ; B-fragments read DIRECTLY from
//                    global (Wsub is L2-resident), no Bs LDS, no phase-B barriers
//   final layer writes fp32 to d_out.
// ---------------------------------------------------------------------------

typedef __attribute__((ext_vector_type(8))) short short8;
typedef __attribute__((ext_vector_type(4))) float f32x4;

__device__ inline unsigned short f2bf(float f) {
    union { float f; unsigned u; } v; v.f = f;
    unsigned r = v.u + 0x7fffu + ((v.u >> 16) & 1u);   // RNE
    return (unsigned short)(r >> 16);
}
__device__ inline float bflo(unsigned u) { return __uint_as_float(u << 16); }
__device__ inline float bfhi(unsigned u) { return __uint_as_float(u & 0xffff0000u); }

#define ACC8(v) { acc[0]+=bflo(v.x); acc[1]+=bfhi(v.x); acc[2]+=bflo(v.y); acc[3]+=bfhi(v.y); \
                  acc[4]+=bflo(v.z); acc[5]+=bfhi(v.z); acc[6]+=bflo(v.w); acc[7]+=bfhi(v.w); }

// ---------------- prep: x->bf16, hist, W->subtiled bf16 ----------------
__global__ __launch_bounds__(256) void prep_kernel(
    const float* __restrict__ x, const int* __restrict__ dst,
    const float* __restrict__ W1, const float* __restrict__ W2,
    const float* __restrict__ W3,
    unsigned short* __restrict__ xb, int* __restrict__ cnt,
    unsigned short* __restrict__ Ws1, unsigned short* __restrict__ Ws2,
    unsigned short* __restrict__ Ws3, int M, int nE)
{
    const int i  = blockIdx.x * 256 + threadIdx.x;
    const int nx = M * 16;
    if (i < nx) {
        const float4* xf = reinterpret_cast<const float4*>(x);
        float4 a = xf[2*i], b = xf[2*i + 1];
        uint4 o;
        o.x = (unsigned)f2bf(a.x) | ((unsigned)f2bf(a.y) << 16);
        o.y = (unsigned)f2bf(a.z) | ((unsigned)f2bf(a.w) << 16);
        o.z = (unsigned)f2bf(b.x) | ((unsigned)f2bf(b.y) << 16);
        o.w = (unsigned)f2bf(b.z) | ((unsigned)f2bf(b.w) << 16);
        reinterpret_cast<uint4*>(xb)[i] = o;
    } else if (i < nx + nE) {
        atomicAdd(&cnt[dst[i - nx]], 1);
    } else {
        int j = i - nx - nE;
        const float* W; unsigned short* D;
        if (j < 32768)       { W = W1; D = Ws1; }
        else if (j < 98304)  { W = W2; D = Ws2; j -= 32768; }
        else if (j < 163840) { W = W3; D = Ws3; j -= 98304; }
        else return;
        const int k = j >> 8, n = j & 255;
        // Wsub[k/8][n][k%8] = bf16(W[k][n])
        D[((size_t)(k >> 3) * 256 + n) * 8 + (k & 7)] = f2bf(W[(size_t)k * 256 + n]);
    }
}

// ---------------- CSR scan + scatter ----------------

__global__ __launch_bounds__(1024) void scan1_kernel(
    const int* __restrict__ cnt, int* __restrict__ excl,
    int* __restrict__ bsum, int n)
{
    __shared__ int sh[1024];
    const int tid = threadIdx.x;
    const int i = blockIdx.x * 1024 + tid;
    int v = (i < n) ? cnt[i] : 0;
    sh[tid] = v;
    __syncthreads();
    #pragma unroll
    for (int off = 1; off < 1024; off <<= 1) {
        int t = (tid >= off) ? sh[tid - off] : 0;
        __syncthreads();
        sh[tid] += t;
        __syncthreads();
    }
    if (i < n) excl[i] = sh[tid] - v;
    if (tid == 1023) bsum[blockIdx.x] = sh[1023];
}

__global__ __launch_bounds__(64) void scan2_kernel(
    const int* __restrict__ bsum, int* __restrict__ boffs, int nb)
{
    __shared__ int sh[64];
    const int tid = threadIdx.x;
    int v = (tid < nb) ? bsum[tid] : 0;
    sh[tid] = v;
    __syncthreads();
    #pragma unroll
    for (int off = 1; off < 64; off <<= 1) {
        int t = (tid >= off) ? sh[tid - off] : 0;
        __syncthreads();
        sh[tid] += t;
        __syncthreads();
    }
    boffs[tid] = sh[tid] - v;  // exclusive
}

__global__ __launch_bounds__(1024) void scan3_kernel(
    const int* __restrict__ excl, const int* __restrict__ boffs,
    int* __restrict__ row_start, int* __restrict__ cursor, int n, int nE)
{
    const int i = blockIdx.x * 1024 + threadIdx.x;
    if (i < n) {
        int v = excl[i] + boffs[blockIdx.x];
        row_start[i] = v;
        cursor[i] = v;
    }
    if (i == 0) row_start[n] = nE;
}

__global__ __launch_bounds__(256) void build_adj_kernel(
    const int* __restrict__ src, const int* __restrict__ dst,
    int* __restrict__ cursor, int* __restrict__ adj, int nE)
{
    int e = blockIdx.x * 256 + threadIdx.x;
    if (e < nE) {
        int p = atomicAdd(&cursor[dst[e]], 1);
        adj[p] = src[e];
    }
}

// ---------------- fused layer: aggregate 32 rows + GEMM(32x256) ------------
// Hs: padded k-subtiled A tile [CIN/8][33][8] -> write banks 4*(c8+r)%32.
// B fragments: read per K-step straight from global Wsub (L2-resident).

template <int CIN, int RELU, int BF16OUT>
__global__ __launch_bounds__(256) void fused_layer(
    const unsigned short* __restrict__ X,
    const int* __restrict__ row_start, const int* __restrict__ adj,
    const unsigned short* __restrict__ Wsub,
    const float* __restrict__ bias, const float* __restrict__ eps_arr,
    int layer, void* __restrict__ out, int M)
{
    constexpr int KB     = CIN / 8;    // kblocks
    constexpr int S      = CIN / 32;   // K-steps
    constexpr int TPN    = CIN / 8;    // lanes per node in agg
    constexpr int NPB    = 256 / TPN;  // nodes per agg pass
    constexpr int PASSES = 32 / NPB;

    __shared__ __align__(16) unsigned short Hs[KB][33][8];

    const int t    = threadIdx.x;
    const int bm   = blockIdx.x * 32;
    const int w    = t >> 6, lane = t & 63;
    const int lr   = lane & 15, ko = lane >> 4;

    // ---- phase A: aggregate 32 rows into Hs ----
    const uint4* __restrict__ X4 = reinterpret_cast<const uint4*>(X);
    const int c8 = t & (TPN - 1);
    const int rb = t / TPN;
    #pragma unroll
    for (int p = 0; p < PASSES; ++p) {
        const int r = p * NPB + rb;
        const int node = bm + r;
        uint4 ov = {0, 0, 0, 0};
        if (node < M) {
            float acc[8] = {};
            const int s0 = row_start[node], s1 = row_start[node + 1];
            int j = s0;
            for (; j + 3 < s1; j += 4) {
                const int a0 = adj[j], a1 = adj[j+1], a2 = adj[j+2], a3 = adj[j+3];
                const uint4 v0 = X4[(size_t)a0 * TPN + c8];
                const uint4 v1 = X4[(size_t)a1 * TPN + c8];
                const uint4 v2 = X4[(size_t)a2 * TPN + c8];
                const uint4 v3 = X4[(size_t)a3 * TPN + c8];
                ACC8(v0); ACC8(v1); ACC8(v2); ACC8(v3);
            }
            for (; j < s1; ++j) {
                const uint4 v = X4[(size_t)adj[j] * TPN + c8];
                ACC8(v);
            }
            const uint4 xv = X4[(size_t)node * TPN + c8];
            const float epsv = 1.0f + eps_arr[layer];
            float o[8];
            o[0] = epsv * bflo(xv.x) + acc[0]; o[1] = epsv * bfhi(xv.x) + acc[1];
            o[2] = epsv * bflo(xv.y) + acc[2]; o[3] = epsv * bfhi(xv.y) + acc[3];
            o[4] = epsv * bflo(xv.z) + acc[4]; o[5] = epsv * bfhi(xv.z) + acc[5];
            o[6] = epsv * bflo(xv.w) + acc[6]; o[7] = epsv * bfhi(xv.w) + acc[7];
            ov.x = (unsigned)f2bf(o[0]) | ((unsigned)f2bf(o[1]) << 16);
            ov.y = (unsigned)f2bf(o[2]) | ((unsigned)f2bf(o[3]) << 16);
            ov.z = (unsigned)f2bf(o[4]) | ((unsigned)f2bf(o[5]) << 16);
            ov.w = (unsigned)f2bf(o[6]) | ((unsigned)f2bf(o[7]) << 16);
        }
        *reinterpret_cast<uint4*>(&Hs[c8][r][0]) = ov;
    }

    __syncthreads();   // Hs complete; no further barriers needed

    // ---- phase B: GEMM, B from global (L2) ----
    f32x4 acc[2][4] = {};
    #pragma unroll
    for (int s = 0; s < S; ++s) {
        short8 bf8[4];
        #pragma unroll
        for (int fn = 0; fn < 4; ++fn)
            bf8[fn] = *reinterpret_cast<const short8*>(
                Wsub + ((size_t)(s*4 + ko) * 256 + w*64 + fn*16 + lr) * 8);
        short8 af[2];
        #pragma unroll
        for (int fm = 0; fm < 2; ++fm)
            af[fm] = *reinterpret_cast<const short8*>(&Hs[s*4 + ko][fm*16 + lr][0]);
        #pragma unroll
        for (int fm = 0; fm < 2; ++fm)
            #pragma unroll
            for (int fn = 0; fn < 4; ++fn)
                acc[fm][fn] = __builtin_amdgcn_mfma_f32_16x16x32_bf16(
                    af[fm], bf8[fn], acc[fm][fn], 0, 0, 0);
    }

    // ---- epilogue: C/D layout col = lane&15, row = (lane>>4)*4 + r ----
    #pragma unroll
    for (int fn = 0; fn < 4; ++fn) {
        const int col = w*64 + fn*16 + lr;
        const float bb = bias[col];
        #pragma unroll
        for (int fm = 0; fm < 2; ++fm) {
            const int rbase = bm + fm*16 + ko*4;
            #pragma unroll
            for (int r = 0; r < 4; ++r) {
                const int row = rbase + r;
                if (row < M) {
                    float v = acc[fm][fn][r] + bb;
                    if (RELU) v = fmaxf(v, 0.f);
                    if (BF16OUT)
                        ((unsigned short*)out)[(size_t)row * 256 + col] = f2bf(v);
                    else
                        ((float*)out)[(size_t)row * 256 + col] = v;
                }
            }
        }
    }
}

// ---------------- launch ----------------

extern "C" void kernel_launch(void* const* d_in, const int* in_sizes, int n_in,
                              void* d_out, int out_size, void* d_ws, size_t ws_size,
                              hipStream_t stream)
{
    const float* x   = (const float*)d_in[0];
    const int*   ei  = (const int*)  d_in[1];
    const float* W1  = (const float*)d_in[2];
    const float* b1  = (const float*)d_in[3];
    const float* W2  = (const float*)d_in[4];
    const float* b2  = (const float*)d_in[5];
    const float* W3  = (const float*)d_in[6];
    const float* b3  = (const float*)d_in[7];
    const float* eps = (const float*)d_in[8];

    const int M  = in_sizes[0] / 128;   // 50000
    const int nE = in_sizes[1] / 2;     // 800000
    const int Mp = ((M + 127) / 128) * 128;
    const int* srcI = ei;
    const int* dstI = ei + nE;

    // workspace layout
    char* p = (char*)d_ws;
    unsigned short* xb  = (unsigned short*)p; p += (size_t)M  * 128 * 2;
    unsigned short* h1  = (unsigned short*)p; p += (size_t)Mp * 256 * 2;
    unsigned short* h2  = (unsigned short*)p; p += (size_t)Mp * 256 * 2;
    unsigned short* Ws1 = (unsigned short*)p; p += (size_t)128 * 256 * 2;
    unsigned short* Ws2 = (unsigned short*)p; p += (size_t)256 * 256 * 2;
    unsigned short* Ws3 = (unsigned short*)p; p += (size_t)256 * 256 * 2;
    int* cnt       = (int*)p; p += (size_t)M * 4;
    int* excl      = (int*)p; p += (size_t)M * 4;
    int* bsum      = (int*)p; p += 64 * 4;
    int* boffs     = (int*)p; p += 64 * 4;
    int* row_start = (int*)p; p += (size_t)(M + 2) * 4;
    int* cursor    = (int*)p; p += (size_t)M * 4;
    int* adj       = (int*)p; p += (size_t)nE * 4;

    const int nbl = (M + 1023) / 1024;   // 49

    hipMemsetAsync(cnt, 0, (size_t)M * sizeof(int), stream);
    {
        const int total = M * 16 + nE + 163840;
        prep_kernel<<<(total + 255) / 256, 256, 0, stream>>>(
            x, dstI, W1, W2, W3, xb, cnt, Ws1, Ws2, Ws3, M, nE);
    }
    scan1_kernel<<<nbl, 1024, 0, stream>>>(cnt, excl, bsum, M);
    scan2_kernel<<<1, 64, 0, stream>>>(bsum, boffs, nbl);
    scan3_kernel<<<nbl, 1024, 0, stream>>>(excl, boffs, row_start, cursor, M, nE);
    build_adj_kernel<<<(nE + 255) / 256, 256, 0, stream>>>(srcI, dstI, cursor, adj, nE);

    const int nblk = (M + 31) / 32;   // 1563

    fused_layer<128, 1, 1><<<nblk, 256, 0, stream>>>(
        xb, row_start, adj, Ws1, b1, eps, 0, h1, M);
    fused_layer<256, 1, 1><<<nblk, 256, 0, stream>>>(
        h1, row_start, adj, Ws2, b2, eps, 1, h2, M);
    fused_layer<256, 0, 0><<<nblk, 256, 0, stream>>>(
        h2, row_start, adj, Ws3, b3, eps, 2, d_out, M);
}

// Round 8
// 311.198 us; speedup vs baseline: 1.0428x; 1.0428x over previous
//
#include <hip/hip_runtime.h>

// ---------------------------------------------------------------------------
// GIN 3-layer forward, fused bf16 pipeline (R8):
//   prep:   convert x->bf16, hist(dst), convert W1..3 -> k-subtiled bf16
//   CSR:    scan -> bucket scatter
//   layer:  ONE kernel, block = BM node rows where BM = one gather pass:
//             CIN=128 -> BM=16 (3125 blocks), CIN=256 -> BM=8 (6250 blocks)
//           phase A: H[BM][CIN] = (1+eps)x + gather-sum -> LDS (1 pass/thread)
//           phase B: out[BM][256] = H @ W + b ; B-frags straight from global
//                    (Wsub L2-resident). One barrier total.
//   final layer writes fp32 to d_out.
//   NOTE: assumes M % 16 == 0 (M = 50000 ✓).
// ---------------------------------------------------------------------------

typedef __attribute__((ext_vector_type(8))) short short8;
typedef __attribute__((ext_vector_type(4))) float f32x4;

__device__ inline unsigned short f2bf(float f) {
    union { float f; unsigned u; } v; v.f = f;
    unsigned r = v.u + 0x7fffu + ((v.u >> 16) & 1u);   // RNE
    return (unsigned short)(r >> 16);
}
__device__ inline float bflo(unsigned u) { return __uint_as_float(u << 16); }
__device__ inline float bfhi(unsigned u) { return __uint_as_float(u & 0xffff0000u); }

#define ACC8(v) { acc[0]+=bflo(v.x); acc[1]+=bfhi(v.x); acc[2]+=bflo(v.y); acc[3]+=bfhi(v.y); \
                  acc[4]+=bflo(v.z); acc[5]+=bfhi(v.z); acc[6]+=bflo(v.w); acc[7]+=bfhi(v.w); }

// ---------------- prep: x->bf16, hist, W->subtiled bf16 ----------------
__global__ __launch_bounds__(256) void prep_kernel(
    const float* __restrict__ x, const int* __restrict__ dst,
    const float* __restrict__ W1, const float* __restrict__ W2,
    const float* __restrict__ W3,
    unsigned short* __restrict__ xb, int* __restrict__ cnt,
    unsigned short* __restrict__ Ws1, unsigned short* __restrict__ Ws2,
    unsigned short* __restrict__ Ws3, int M, int nE)
{
    const int i  = blockIdx.x * 256 + threadIdx.x;
    const int nx = M * 16;
    if (i < nx) {
        const float4* xf = reinterpret_cast<const float4*>(x);
        float4 a = xf[2*i], b = xf[2*i + 1];
        uint4 o;
        o.x = (unsigned)f2bf(a.x) | ((unsigned)f2bf(a.y) << 16);
        o.y = (unsigned)f2bf(a.z) | ((unsigned)f2bf(a.w) << 16);
        o.z = (unsigned)f2bf(b.x) | ((unsigned)f2bf(b.y) << 16);
        o.w = (unsigned)f2bf(b.z) | ((unsigned)f2bf(b.w) << 16);
        reinterpret_cast<uint4*>(xb)[i] = o;
    } else if (i < nx + nE) {
        atomicAdd(&cnt[dst[i - nx]], 1);
    } else {
        int j = i - nx - nE;
        const float* W; unsigned short* D;
        if (j < 32768)       { W = W1; D = Ws1; }
        else if (j < 98304)  { W = W2; D = Ws2; j -= 32768; }
        else if (j < 163840) { W = W3; D = Ws3; j -= 98304; }
        else return;
        const int k = j >> 8, n = j & 255;
        // Wsub[k/8][n][k%8] = bf16(W[k][n])
        D[((size_t)(k >> 3) * 256 + n) * 8 + (k & 7)] = f2bf(W[(size_t)k * 256 + n]);
    }
}

// ---------------- CSR scan + scatter ----------------

__global__ __launch_bounds__(1024) void scan1_kernel(
    const int* __restrict__ cnt, int* __restrict__ excl,
    int* __restrict__ bsum, int n)
{
    __shared__ int sh[1024];
    const int tid = threadIdx.x;
    const int i = blockIdx.x * 1024 + tid;
    int v = (i < n) ? cnt[i] : 0;
    sh[tid] = v;
    __syncthreads();
    #pragma unroll
    for (int off = 1; off < 1024; off <<= 1) {
        int t = (tid >= off) ? sh[tid - off] : 0;
        __syncthreads();
        sh[tid] += t;
        __syncthreads();
    }
    if (i < n) excl[i] = sh[tid] - v;
    if (tid == 1023) bsum[blockIdx.x] = sh[1023];
}

__global__ __launch_bounds__(64) void scan2_kernel(
    const int* __restrict__ bsum, int* __restrict__ boffs, int nb)
{
    __shared__ int sh[64];
    const int tid = threadIdx.x;
    int v = (tid < nb) ? bsum[tid] : 0;
    sh[tid] = v;
    __syncthreads();
    #pragma unroll
    for (int off = 1; off < 64; off <<= 1) {
        int t = (tid >= off) ? sh[tid - off] : 0;
        __syncthreads();
        sh[tid] += t;
        __syncthreads();
    }
    boffs[tid] = sh[tid] - v;  // exclusive
}

__global__ __launch_bounds__(1024) void scan3_kernel(
    const int* __restrict__ excl, const int* __restrict__ boffs,
    int* __restrict__ row_start, int* __restrict__ cursor, int n, int nE)
{
    const int i = blockIdx.x * 1024 + threadIdx.x;
    if (i < n) {
        int v = excl[i] + boffs[blockIdx.x];
        row_start[i] = v;
        cursor[i] = v;
    }
    if (i == 0) row_start[n] = nE;
}

__global__ __launch_bounds__(256) void build_adj_kernel(
    const int* __restrict__ src, const int* __restrict__ dst,
    int* __restrict__ cursor, int* __restrict__ adj, int nE)
{
    int e = blockIdx.x * 256 + threadIdx.x;
    if (e < nE) {
        int p = atomicAdd(&cursor[dst[e]], 1);
        adj[p] = src[e];
    }
}

// ---------------- fused layer: aggregate BM rows + GEMM(BMx256) ------------
// BM = NPB = 2048/CIN: one gather pass, one barrier.
// Hs: padded k-subtiled A tile [CIN/8][17][8].
// B fragments: read per K-step straight from global Wsub (L2-resident).

template <int CIN, int RELU, int BF16OUT>
__global__ __launch_bounds__(256) void fused_layer(
    const unsigned short* __restrict__ X,
    const int* __restrict__ row_start, const int* __restrict__ adj,
    const unsigned short* __restrict__ Wsub,
    const float* __restrict__ bias, const float* __restrict__ eps_arr,
    int layer, void* __restrict__ out, int M)
{
    constexpr int KB  = CIN / 8;     // kblocks
    constexpr int S   = CIN / 32;    // K-steps
    constexpr int TPN = CIN / 8;     // lanes per node in agg
    constexpr int BM  = 256 / TPN;   // nodes per block (= one pass)

    __shared__ __align__(16) unsigned short Hs[KB][17][8];

    const int t    = threadIdx.x;
    const int bm   = blockIdx.x * BM;
    const int w    = t >> 6, lane = t & 63;
    const int lr   = lane & 15, ko = lane >> 4;

    // ---- phase A: aggregate BM rows into Hs (single pass) ----
    const uint4* __restrict__ X4 = reinterpret_cast<const uint4*>(X);
    const int c8 = t & (TPN - 1);
    const int rb = t / TPN;
    {
        const int node = bm + rb;
        uint4 ov = {0, 0, 0, 0};
        if (node < M) {
            float acc[8] = {};
            const int s0 = row_start[node], s1 = row_start[node + 1];
            int j = s0;
            for (; j + 3 < s1; j += 4) {
                const int a0 = adj[j], a1 = adj[j+1], a2 = adj[j+2], a3 = adj[j+3];
                const uint4 v0 = X4[(size_t)a0 * TPN + c8];
                const uint4 v1 = X4[(size_t)a1 * TPN + c8];
                const uint4 v2 = X4[(size_t)a2 * TPN + c8];
                const uint4 v3 = X4[(size_t)a3 * TPN + c8];
                ACC8(v0); ACC8(v1); ACC8(v2); ACC8(v3);
            }
            for (; j < s1; ++j) {
                const uint4 v = X4[(size_t)adj[j] * TPN + c8];
                ACC8(v);
            }
            const uint4 xv = X4[(size_t)node * TPN + c8];
            const float epsv = 1.0f + eps_arr[layer];
            float o[8];
            o[0] = epsv * bflo(xv.x) + acc[0]; o[1] = epsv * bfhi(xv.x) + acc[1];
            o[2] = epsv * bflo(xv.y) + acc[2]; o[3] = epsv * bfhi(xv.y) + acc[3];
            o[4] = epsv * bflo(xv.z) + acc[4]; o[5] = epsv * bfhi(xv.z) + acc[5];
            o[6] = epsv * bflo(xv.w) + acc[6]; o[7] = epsv * bfhi(xv.w) + acc[7];
            ov.x = (unsigned)f2bf(o[0]) | ((unsigned)f2bf(o[1]) << 16);
            ov.y = (unsigned)f2bf(o[2]) | ((unsigned)f2bf(o[3]) << 16);
            ov.z = (unsigned)f2bf(o[4]) | ((unsigned)f2bf(o[5]) << 16);
            ov.w = (unsigned)f2bf(o[6]) | ((unsigned)f2bf(o[7]) << 16);
        }
        *reinterpret_cast<uint4*>(&Hs[c8][rb][0]) = ov;
    }

    __syncthreads();   // Hs complete; no further barriers

    // ---- phase B: GEMM, B from global (L2) ----
    // A-frag row = lr % BM (BM=8: rows 8..15 are broadcast duplicates,
    // their outputs are discarded in the epilogue).
    f32x4 acc[4] = {{0,0,0,0},{0,0,0,0},{0,0,0,0},{0,0,0,0}};
    const int arow = lr & (BM - 1);
    #pragma unroll
    for (int s = 0; s < S; ++s) {
        short8 bf8[4];
        #pragma unroll
        for (int fn = 0; fn < 4; ++fn)
            bf8[fn] = *reinterpret_cast<const short8*>(
                Wsub + ((size_t)(s*4 + ko) * 256 + w*64 + fn*16 + lr) * 8);
        const short8 af = *reinterpret_cast<const short8*>(&Hs[s*4 + ko][arow][0]);
        #pragma unroll
        for (int fn = 0; fn < 4; ++fn)
            acc[fn] = __builtin_amdgcn_mfma_f32_16x16x32_bf16(
                af, bf8[fn], acc[fn], 0, 0, 0);
    }

    // ---- epilogue: C/D layout col = lane&15, row = (lane>>4)*4 + r ----
    #pragma unroll
    for (int fn = 0; fn < 4; ++fn) {
        const int col = w*64 + fn*16 + lr;
        const float bb = bias[col];
        #pragma unroll
        for (int r = 0; r < 4; ++r) {
            const int row = ko*4 + r;          // 0..15
            if (row < BM) {
                const int grow = bm + row;
                if (grow < M) {
                    float v = acc[fn][r] + bb;
                    if (RELU) v = fmaxf(v, 0.f);
                    if (BF16OUT)
                        ((unsigned short*)out)[(size_t)grow * 256 + col] = f2bf(v);
                    else
                        ((float*)out)[(size_t)grow * 256 + col] = v;
                }
            }
        }
    }
}

// ---------------- launch ----------------

extern "C" void kernel_launch(void* const* d_in, const int* in_sizes, int n_in,
                              void* d_out, int out_size, void* d_ws, size_t ws_size,
                              hipStream_t stream)
{
    const float* x   = (const float*)d_in[0];
    const int*   ei  = (const int*)  d_in[1];
    const float* W1  = (const float*)d_in[2];
    const float* b1  = (const float*)d_in[3];
    const float* W2  = (const float*)d_in[4];
    const float* b2  = (const float*)d_in[5];
    const float* W3  = (const float*)d_in[6];
    const float* b3  = (const float*)d_in[7];
    const float* eps = (const float*)d_in[8];

    const int M  = in_sizes[0] / 128;   // 50000
    const int nE = in_sizes[1] / 2;     // 800000
    const int* srcI = ei;
    const int* dstI = ei + nE;

    // workspace layout
    char* p = (char*)d_ws;
    unsigned short* xb  = (unsigned short*)p; p += (size_t)M * 128 * 2;
    unsigned short* h1  = (unsigned short*)p; p += (size_t)M * 256 * 2;
    unsigned short* h2  = (unsigned short*)p; p += (size_t)M * 256 * 2;
    unsigned short* Ws1 = (unsigned short*)p; p += (size_t)128 * 256 * 2;
    unsigned short* Ws2 = (unsigned short*)p; p += (size_t)256 * 256 * 2;
    unsigned short* Ws3 = (unsigned short*)p; p += (size_t)256 * 256 * 2;
    int* cnt       = (int*)p; p += (size_t)M * 4;
    int* excl      = (int*)p; p += (size_t)M * 4;
    int* bsum      = (int*)p; p += 64 * 4;
    int* boffs     = (int*)p; p += 64 * 4;
    int* row_start = (int*)p; p += (size_t)(M + 2) * 4;
    int* cursor    = (int*)p; p += (size_t)M * 4;
    int* adj       = (int*)p; p += (size_t)nE * 4;

    const int nbl = (M + 1023) / 1024;   // 49

    hipMemsetAsync(cnt, 0, (size_t)M * sizeof(int), stream);
    {
        const int total = M * 16 + nE + 163840;
        prep_kernel<<<(total + 255) / 256, 256, 0, stream>>>(
            x, dstI, W1, W2, W3, xb, cnt, Ws1, Ws2, Ws3, M, nE);
    }
    scan1_kernel<<<nbl, 1024, 0, stream>>>(cnt, excl, bsum, M);
    scan2_kernel<<<1, 64, 0, stream>>>(bsum, boffs, nbl);
    scan3_kernel<<<nbl, 1024, 0, stream>>>(excl, boffs, row_start, cursor, M, nE);
    build_adj_kernel<<<(nE + 255) / 256, 256, 0, stream>>>(srcI, dstI, cursor, adj, nE);

    // layer 1: CIN=128 -> BM=16 -> 3125 blocks
    fused_layer<128, 1, 1><<<(M + 15) / 16, 256, 0, stream>>>(
        xb, row_start, adj, Ws1, b1, eps, 0, h1, M);
    // layer 2: CIN=256 -> BM=8 -> 6250 blocks
    fused_layer<256, 1, 1><<<(M + 7) / 8, 256, 0, stream>>>(
        h1, row_start, adj, Ws2, b2, eps, 1, h2, M);
    // layer 3: CIN=256, fp32 out
    fused_layer<256, 0, 0><<<(M + 7) / 8, 256, 0, stream>>>(
        h2, row_start, adj, Ws3, b3, eps, 2, d_out, M);
}

// Round 9
// 298.066 us; speedup vs baseline: 1.0888x; 1.0441x over previous
//
#include <hip/hip_runtime.h>

// ---------------------------------------------------------------------------
// GIN 3-layer forward, fused bf16 pipeline (R9):
//   prep:   convert x->bf16, hist(dst), convert W1..3 -> k-subtiled bf16
//   CSR:    scan -> bucket scatter
//   layer:  ONE kernel, block = 16 node rows (BM=16, M%16==0):
//           phase A: H[16][CIN] = (1+eps)x + gather-sum -> LDS
//                    (CIN=128: 1 pass, CIN=256: 2 passes)
//           phase B: out[16][256] = H @ W + b ; B-frags straight from global
//                    (Wsub L2-resident); bias folded into acc init.
//           epilogue: repack C via LDS -> coalesced 16B stores.
// ---------------------------------------------------------------------------

typedef __attribute__((ext_vector_type(8))) short short8;
typedef __attribute__((ext_vector_type(4))) float f32x4;

__device__ inline unsigned short f2bf(float f) {
    union { float f; unsigned u; } v; v.f = f;
    unsigned r = v.u + 0x7fffu + ((v.u >> 16) & 1u);   // RNE
    return (unsigned short)(r >> 16);
}
__device__ inline float bflo(unsigned u) { return __uint_as_float(u << 16); }
__device__ inline float bfhi(unsigned u) { return __uint_as_float(u & 0xffff0000u); }

#define ACC8(v) { acc[0]+=bflo(v.x); acc[1]+=bfhi(v.x); acc[2]+=bflo(v.y); acc[3]+=bfhi(v.y); \
                  acc[4]+=bflo(v.z); acc[5]+=bfhi(v.z); acc[6]+=bflo(v.w); acc[7]+=bfhi(v.w); }

// ---------------- prep: x->bf16, hist, W->subtiled bf16 ----------------
__global__ __launch_bounds__(256) void prep_kernel(
    const float* __restrict__ x, const int* __restrict__ dst,
    const float* __restrict__ W1, const float* __restrict__ W2,
    const float* __restrict__ W3,
    unsigned short* __restrict__ xb, int* __restrict__ cnt,
    unsigned short* __restrict__ Ws1, unsigned short* __restrict__ Ws2,
    unsigned short* __restrict__ Ws3, int M, int nE)
{
    const int i  = blockIdx.x * 256 + threadIdx.x;
    const int nx = M * 16;
    if (i < nx) {
        const float4* xf = reinterpret_cast<const float4*>(x);
        float4 a = xf[2*i], b = xf[2*i + 1];
        uint4 o;
        o.x = (unsigned)f2bf(a.x) | ((unsigned)f2bf(a.y) << 16);
        o.y = (unsigned)f2bf(a.z) | ((unsigned)f2bf(a.w) << 16);
        o.z = (unsigned)f2bf(b.x) | ((unsigned)f2bf(b.y) << 16);
        o.w = (unsigned)f2bf(b.z) | ((unsigned)f2bf(b.w) << 16);
        reinterpret_cast<uint4*>(xb)[i] = o;
    } else if (i < nx + nE) {
        atomicAdd(&cnt[dst[i - nx]], 1);
    } else {
        int j = i - nx - nE;
        const float* W; unsigned short* D;
        if (j < 32768)       { W = W1; D = Ws1; }
        else if (j < 98304)  { W = W2; D = Ws2; j -= 32768; }
        else if (j < 163840) { W = W3; D = Ws3; j -= 98304; }
        else return;
        const int k = j >> 8, n = j & 255;
        // Wsub[k/8][n][k%8] = bf16(W[k][n])
        D[((size_t)(k >> 3) * 256 + n) * 8 + (k & 7)] = f2bf(W[(size_t)k * 256 + n]);
    }
}

// ---------------- CSR scan + scatter ----------------

__global__ __launch_bounds__(1024) void scan1_kernel(
    const int* __restrict__ cnt, int* __restrict__ excl,
    int* __restrict__ bsum, int n)
{
    __shared__ int sh[1024];
    const int tid = threadIdx.x;
    const int i = blockIdx.x * 1024 + tid;
    int v = (i < n) ? cnt[i] : 0;
    sh[tid] = v;
    __syncthreads();
    #pragma unroll
    for (int off = 1; off < 1024; off <<= 1) {
        int t = (tid >= off) ? sh[tid - off] : 0;
        __syncthreads();
        sh[tid] += t;
        __syncthreads();
    }
    if (i < n) excl[i] = sh[tid] - v;
    if (tid == 1023) bsum[blockIdx.x] = sh[1023];
}

__global__ __launch_bounds__(64) void scan2_kernel(
    const int* __restrict__ bsum, int* __restrict__ boffs, int nb)
{
    __shared__ int sh[64];
    const int tid = threadIdx.x;
    int v = (tid < nb) ? bsum[tid] : 0;
    sh[tid] = v;
    __syncthreads();
    #pragma unroll
    for (int off = 1; off < 64; off <<= 1) {
        int t = (tid >= off) ? sh[tid - off] : 0;
        __syncthreads();
        sh[tid] += t;
        __syncthreads();
    }
    boffs[tid] = sh[tid] - v;  // exclusive
}

__global__ __launch_bounds__(1024) void scan3_kernel(
    const int* __restrict__ excl, const int* __restrict__ boffs,
    int* __restrict__ row_start, int* __restrict__ cursor, int n, int nE)
{
    const int i = blockIdx.x * 1024 + threadIdx.x;
    if (i < n) {
        int v = excl[i] + boffs[blockIdx.x];
        row_start[i] = v;
        cursor[i] = v;
    }
    if (i == 0) row_start[n] = nE;
}

__global__ __launch_bounds__(256) void build_adj_kernel(
    const int* __restrict__ src, const int* __restrict__ dst,
    int* __restrict__ cursor, int* __restrict__ adj, int nE)
{
    int e = blockIdx.x * 256 + threadIdx.x;
    if (e < nE) {
        int p = atomicAdd(&cursor[dst[e]], 1);
        adj[p] = src[e];
    }
}

// ---------------- fused layer: aggregate 16 rows + GEMM(16x256) ------------
// Hs: padded k-subtiled A tile [CIN/8][17][8].
// B fragments: read per K-step straight from global Wsub (L2-resident).
// Epilogue repacks C via LDS into coalesced 16B stores.

template <int CIN, int RELU, int BF16OUT>
__global__ __launch_bounds__(256) void fused_layer(
    const unsigned short* __restrict__ X,
    const int* __restrict__ row_start, const int* __restrict__ adj,
    const unsigned short* __restrict__ Wsub,
    const float* __restrict__ bias, const float* __restrict__ eps_arr,
    int layer, void* __restrict__ out, int M)
{
    constexpr int KB     = CIN / 8;     // kblocks
    constexpr int S      = CIN / 32;    // K-steps
    constexpr int TPN    = CIN / 8;     // lanes per node in agg
    constexpr int NPB    = 256 / TPN;   // nodes per pass
    constexpr int PASSES = 16 / NPB;    // BM=16

    __shared__ __align__(16) unsigned short Hs[KB][17][8];
    __shared__ __align__(16) unsigned short OutS[BF16OUT ? 16 : 1][BF16OUT ? 264 : 1];
    __shared__ __align__(16) float          OutF[BF16OUT ? 1 : 16][BF16OUT ? 1 : 260];

    const int t    = threadIdx.x;
    const int bm   = blockIdx.x * 16;
    const int w    = t >> 6, lane = t & 63;
    const int lr   = lane & 15, ko = lane >> 4;

    // ---- phase A: aggregate 16 rows into Hs ----
    const uint4* __restrict__ X4 = reinterpret_cast<const uint4*>(X);
    const int c8 = t & (TPN - 1);
    const int rb = t / TPN;
    const float epsv = 1.0f + eps_arr[layer];
    #pragma unroll
    for (int p = 0; p < PASSES; ++p) {
        const int r = p * NPB + rb;
        const int node = bm + r;
        uint4 ov = {0, 0, 0, 0};
        if (node < M) {
            float acc[8] = {};
            const int s0 = row_start[node], s1 = row_start[node + 1];
            int j = s0;
            for (; j + 3 < s1; j += 4) {
                const int a0 = adj[j], a1 = adj[j+1], a2 = adj[j+2], a3 = adj[j+3];
                const uint4 v0 = X4[(size_t)a0 * TPN + c8];
                const uint4 v1 = X4[(size_t)a1 * TPN + c8];
                const uint4 v2 = X4[(size_t)a2 * TPN + c8];
                const uint4 v3 = X4[(size_t)a3 * TPN + c8];
                ACC8(v0); ACC8(v1); ACC8(v2); ACC8(v3);
            }
            for (; j < s1; ++j) {
                const uint4 v = X4[(size_t)adj[j] * TPN + c8];
                ACC8(v);
            }
            const uint4 xv = X4[(size_t)node * TPN + c8];
            float o[8];
            o[0] = epsv * bflo(xv.x) + acc[0]; o[1] = epsv * bfhi(xv.x) + acc[1];
            o[2] = epsv * bflo(xv.y) + acc[2]; o[3] = epsv * bfhi(xv.y) + acc[3];
            o[4] = epsv * bflo(xv.z) + acc[4]; o[5] = epsv * bfhi(xv.z) + acc[5];
            o[6] = epsv * bflo(xv.w) + acc[6]; o[7] = epsv * bfhi(xv.w) + acc[7];
            ov.x = (unsigned)f2bf(o[0]) | ((unsigned)f2bf(o[1]) << 16);
            ov.y = (unsigned)f2bf(o[2]) | ((unsigned)f2bf(o[3]) << 16);
            ov.z = (unsigned)f2bf(o[4]) | ((unsigned)f2bf(o[5]) << 16);
            ov.w = (unsigned)f2bf(o[6]) | ((unsigned)f2bf(o[7]) << 16);
        }
        *reinterpret_cast<uint4*>(&Hs[c8][r][0]) = ov;
    }

    __syncthreads();   // Hs complete

    // ---- phase B: GEMM, B from global (L2); bias folded into acc init ----
    const int col = w*64 + lr;   // base col for fn=0
    f32x4 acc[4];
    #pragma unroll
    for (int fn = 0; fn < 4; ++fn) {
        const float bb = bias[col + fn*16];
        acc[fn][0] = bb; acc[fn][1] = bb; acc[fn][2] = bb; acc[fn][3] = bb;
    }
    #pragma unroll
    for (int s = 0; s < S; ++s) {
        short8 bf8[4];
        #pragma unroll
        for (int fn = 0; fn < 4; ++fn)
            bf8[fn] = *reinterpret_cast<const short8*>(
                Wsub + ((size_t)(s*4 + ko) * 256 + w*64 + fn*16 + lr) * 8);
        const short8 af = *reinterpret_cast<const short8*>(&Hs[s*4 + ko][lr][0]);
        #pragma unroll
        for (int fn = 0; fn < 4; ++fn)
            acc[fn] = __builtin_amdgcn_mfma_f32_16x16x32_bf16(
                af, bf8[fn], acc[fn], 0, 0, 0);
    }

    // ---- epilogue: C layout col=lane&15, row=(lane>>4)*4+r; repack via LDS ----
    __syncthreads();   // safe to reuse LDS region boundaries (distinct arrays)
    #pragma unroll
    for (int fn = 0; fn < 4; ++fn) {
        #pragma unroll
        for (int r = 0; r < 4; ++r) {
            float v = acc[fn][r];
            if (RELU) v = fmaxf(v, 0.f);
            const int row = ko*4 + r;
            const int c   = w*64 + fn*16 + lr;
            if (BF16OUT) OutS[row][c] = f2bf(v);
            else         OutF[row][c] = v;
        }
    }
    __syncthreads();

    if (BF16OUT) {
        // 16 rows x 512B; thread t: row=t>>4, 2 x 16B chunks
        const int row = t >> 4;
        const int u0  = (t & 15) * 2;
        unsigned short* op = (unsigned short*)out + (size_t)(bm + row) * 256;
        *reinterpret_cast<uint4*>(op + u0*8)     = *reinterpret_cast<const uint4*>(&OutS[row][u0*8]);
        *reinterpret_cast<uint4*>(op + u0*8 + 8) = *reinterpret_cast<const uint4*>(&OutS[row][u0*8 + 8]);
    } else {
        // 16 rows x 1024B; thread t: row=t>>4, 4 x 16B chunks
        const int row = t >> 4;
        const int f0  = (t & 15) * 16;   // first float index
        float* op = (float*)out + (size_t)(bm + row) * 256 + f0;
        #pragma unroll
        for (int i = 0; i < 4; ++i)
            *reinterpret_cast<float4*>(op + i*4) = *reinterpret_cast<const float4*>(&OutF[row][f0 + i*4]);
    }
}

// ---------------- launch ----------------

extern "C" void kernel_launch(void* const* d_in, const int* in_sizes, int n_in,
                              void* d_out, int out_size, void* d_ws, size_t ws_size,
                              hipStream_t stream)
{
    const float* x   = (const float*)d_in[0];
    const int*   ei  = (const int*)  d_in[1];
    const float* W1  = (const float*)d_in[2];
    const float* b1  = (const float*)d_in[3];
    const float* W2  = (const float*)d_in[4];
    const float* b2  = (const float*)d_in[5];
    const float* W3  = (const float*)d_in[6];
    const float* b3  = (const float*)d_in[7];
    const float* eps = (const float*)d_in[8];

    const int M  = in_sizes[0] / 128;   // 50000 (multiple of 16)
    const int nE = in_sizes[1] / 2;     // 800000
    const int* srcI = ei;
    const int* dstI = ei + nE;

    // workspace layout
    char* p = (char*)d_ws;
    unsigned short* xb  = (unsigned short*)p; p += (size_t)M * 128 * 2;
    unsigned short* h1  = (unsigned short*)p; p += (size_t)M * 256 * 2;
    unsigned short* h2  = (unsigned short*)p; p += (size_t)M * 256 * 2;
    unsigned short* Ws1 = (unsigned short*)p; p += (size_t)128 * 256 * 2;
    unsigned short* Ws2 = (unsigned short*)p; p += (size_t)256 * 256 * 2;
    unsigned short* Ws3 = (unsigned short*)p; p += (size_t)256 * 256 * 2;
    int* cnt       = (int*)p; p += (size_t)M * 4;
    int* excl      = (int*)p; p += (size_t)M * 4;
    int* bsum      = (int*)p; p += 64 * 4;
    int* boffs     = (int*)p; p += 64 * 4;
    int* row_start = (int*)p; p += (size_t)(M + 2) * 4;
    int* cursor    = (int*)p; p += (size_t)M * 4;
    int* adj       = (int*)p; p += (size_t)nE * 4;

    const int nbl = (M + 1023) / 1024;   // 49

    hipMemsetAsync(cnt, 0, (size_t)M * sizeof(int), stream);
    {
        const int total = M * 16 + nE + 163840;
        prep_kernel<<<(total + 255) / 256, 256, 0, stream>>>(
            x, dstI, W1, W2, W3, xb, cnt, Ws1, Ws2, Ws3, M, nE);
    }
    scan1_kernel<<<nbl, 1024, 0, stream>>>(cnt, excl, bsum, M);
    scan2_kernel<<<1, 64, 0, stream>>>(bsum, boffs, nbl);
    scan3_kernel<<<nbl, 1024, 0, stream>>>(excl, boffs, row_start, cursor, M, nE);
    build_adj_kernel<<<(nE + 255) / 256, 256, 0, stream>>>(srcI, dstI, cursor, adj, nE);

    const int nblk = (M + 15) / 16;   // 3125

    fused_layer<128, 1, 1><<<nblk, 256, 0, stream>>>(
        xb, row_start, adj, Ws1, b1, eps, 0, h1, M);
    fused_layer<256, 1, 1><<<nblk, 256, 0, stream>>>(
        h1, row_start, adj, Ws2, b2, eps, 1, h2, M);
    fused_layer<256, 0, 0><<<nblk, 256, 0, stream>>>(
        h2, row_start, adj, Ws3, b3, eps, 2, d_out, M);
}